// Round 10
// baseline (519.882 us; speedup 1.0000x reference)
//
#include <hip/hip_runtime.h>
#include <hip/hip_bf16.h>

#define B_ 4
#define S_ 2048
#define E_ 100
#define F_ 64
#define C_ 8922
#define V_ 52000

typedef short bf16x8 __attribute__((ext_vector_type(8)));
typedef short s16x4  __attribute__((ext_vector_type(4)));
typedef float f32x4  __attribute__((ext_vector_type(4)));

#define MFMA16(A, B, C) __builtin_amdgcn_mfma_f32_16x16x32_bf16(A, B, C, 0, 0, 0)
#define LOG2E 1.44269504088896f
#define EXP2F(x) __builtin_amdgcn_exp2f(x)

__device__ inline short bfb(float x) {
    __hip_bfloat16 h = __float2bfloat16(x);
    return *reinterpret_cast<short*>(&h);
}

// ---------------------------------------------------------------------------
// Kernel 0: weight prepack (per-lane MFMA B-fragments, conv k-map
// k = g*4 + (j&3) + ((j>>2)<<4)) + zero num/den/lossAcc/counter.
// ---------------------------------------------------------------------------
__global__ __launch_bounds__(256) void prep_kernel(
    const float* __restrict__ w3, const float* __restrict__ w5,
    const float* __restrict__ w7, const float* __restrict__ w9,
    unsigned short* __restrict__ Wp,
    float* __restrict__ num, float* __restrict__ den,
    float* __restrict__ lossAcc, int* __restrict__ counter)
{
    const int gid = blockIdx.x * 256 + threadIdx.x;   // 0..294911
    if (gid < 4 * B_ * C_) { num[gid] = 0.f; den[gid] = 0.f; }
    if (gid == 0) { *lossAcc = 0.f; *counter = 0; }

    const int j    = gid & 7;
    const int lane = (gid >> 3) & 63;
    const int nt   = (gid >> 9) & 15;
    const int step = gid >> 13;          // 0..35
    const int d    = step >> 2;
    const int ec   = step & 3;
    const int g    = lane >> 4;
    const int lr   = lane & 15;
    const int k    = g * 4 + (j & 3) + ((j >> 2) << 4);
    const int e    = ec * 32 + k;
    const int n    = nt * 16 + lr;
    const int br   = n >> 6;
    const int f    = n & 63;
    const int kb   = 3 + 2 * br;
    const int dp   = d - (3 - br);

    float val = 0.f;
    if (e < E_ && dp >= 0 && dp < kb) {
        const float* w = (br == 0) ? w3 : (br == 1) ? w5 : (br == 2) ? w7 : w9;
        val = w[((size_t)f * E_ + e) * kb + dp];
    }
    Wp[gid] = (unsigned short)bfb(val);
}

// ---------------------------------------------------------------------------
// h bf16 global layouts (byte-identical to R3..R9 validated layouts):
//  hk per (br,b): s*128 + (f*2 ^ ((s&7)<<4))
//  hv per (br,b): (s>>5)*4096 + (f>>4)*1024 + ((s>>4)&1)*512
//                 + ((s>>2)&3)*128 + (s&3)*32 + (f&15)*2
// ---------------------------------------------------------------------------

// ---------------------------------------------------------------------------
// Kernel 1: conv as MFMA GEMM, 16-s tiles, register-dbuf, ROLLED loop
// (R9 fully unrolled 144 global loads -> possible hoist/spill; rolled is
//  the safe shape: static reg names, runtime sp).
// ---------------------------------------------------------------------------
__global__ __launch_bounds__(256, 2) void conv_mfma_kernel(
    const int* __restrict__ x, const float* __restrict__ embed,
    const unsigned short* __restrict__ Wp,
    const float* __restrict__ b3, const float* __restrict__ b5,
    const float* __restrict__ b7, const float* __restrict__ b9,
    char* __restrict__ hkB, char* __restrict__ hvB)
{
    __shared__ unsigned short xeT[24 * 128];   // 6 KB swizzled bf16 tile
    __shared__ float ep[4][16][68];            // 17 KB epilogue bounce

    const int blk  = blockIdx.x;
    const int b    = blk >> 7;
    const int st   = blk & 127;
    const int s0   = st * 16;
    const int tid  = threadIdx.x;
    const int wave = tid >> 6;
    const int lane = tid & 63;
    const int g    = lane >> 4;
    const int lr   = lane & 15;

    // ---- stage xe: 24 rows x 128 e (bf16, row-XOR swizzled)
    for (int task = tid; task < 384; task += 256) {
        const int row = task >> 4;
        const int o   = task & 15;
        const int s   = s0 - 4 + row;
        float v[8];
        #pragma unroll
        for (int i = 0; i < 8; ++i) v[i] = 0.f;
        if (s >= 0 && s < S_ && o < 13) {
            const int tok = x[b * S_ + s];
            const float* er = embed + (size_t)tok * E_ + o * 8;
            if (o < 12) {
                #pragma unroll
                for (int i = 0; i < 8; ++i) v[i] = er[i];
            } else {
                v[0] = er[0]; v[1] = er[1]; v[2] = er[2]; v[3] = er[3];
            }
        }
        unsigned short u[8];
        #pragma unroll
        for (int i = 0; i < 8; ++i) u[i] = (unsigned short)bfb(v[i]);
        const unsigned xr = ((unsigned)(row & 15)) << 3;
        char* base = (char*)xeT + row * 256;
        *(uint2*)(base + (((unsigned)(o * 16)) ^ xr))     = *(const uint2*)&u[0];
        *(uint2*)(base + (((unsigned)(o * 16 + 8)) ^ xr)) = *(const uint2*)&u[4];
    }
    __syncthreads();

    f32x4 acc[4];
    #pragma unroll
    for (int ns = 0; ns < 4; ++ns) acc[ns] = (f32x4){0.f, 0.f, 0.f, 0.f};

    const char* xb = (const char*)xeT;
    const unsigned short* wpb = Wp + ((size_t)wave * 4) * 512 + lane * 8;

#define LOADB(v0, v1, v2, v3, stepv) {                                     \
        const unsigned short* wp = wpb + (size_t)(stepv) * 8192;           \
        v0 = *(const bf16x8*)(wp);        v1 = *(const bf16x8*)(wp + 512); \
        v2 = *(const bf16x8*)(wp + 1024); v3 = *(const bf16x8*)(wp + 1536); }

#define AFLOAD(Afv, stepv) {                                               \
        const int row = lr + ((stepv) >> 2);                               \
        const unsigned xr = ((unsigned)(row & 15)) << 3;                   \
        const unsigned rb = (unsigned)row * 256;                           \
        const unsigned e0 = (unsigned)((((stepv) & 3)) * 64 + g * 8);      \
        const s16x4 lo = *(const s16x4*)(xb + rb + (e0 ^ xr));             \
        const s16x4 hi = *(const s16x4*)(xb + rb + ((e0 + 32) ^ xr));      \
        Afv = __builtin_shufflevector(lo, hi, 0, 1, 2, 3, 4, 5, 6, 7); }

    bf16x8 A0, A1;
    bf16x8 B00, B01, B02, B03, B10, B11, B12, B13;
    LOADB(B00, B01, B02, B03, 0)
    AFLOAD(A0, 0)

    #pragma unroll 1
    for (int sp = 0; sp < 36; sp += 2) {
        LOADB(B10, B11, B12, B13, sp + 1)
        AFLOAD(A1, sp + 1)
        acc[0] = MFMA16(A0, B00, acc[0]);
        acc[1] = MFMA16(A0, B01, acc[1]);
        acc[2] = MFMA16(A0, B02, acc[2]);
        acc[3] = MFMA16(A0, B03, acc[3]);
        if (sp < 34) {
            LOADB(B00, B01, B02, B03, sp + 2)
            AFLOAD(A0, sp + 2)
        }
        acc[0] = MFMA16(A1, B10, acc[0]);
        acc[1] = MFMA16(A1, B11, acc[1]);
        acc[2] = MFMA16(A1, B12, acc[2]);
        acc[3] = MFMA16(A1, B13, acc[3]);
    }

    // ---- epilogue: bias+tanh -> LDS -> vectorized 16B stores to hk & hv
    const float* bias = (wave == 0) ? b3 : (wave == 1) ? b5 : (wave == 2) ? b7 : b9;
    float bia[4];
    #pragma unroll
    for (int ns = 0; ns < 4; ++ns) bia[ns] = bias[ns * 16 + lr];

    #pragma unroll
    for (int ns = 0; ns < 4; ++ns)
        #pragma unroll
        for (int r = 0; r < 4; ++r)
            ep[wave][4 * g + r][ns * 16 + lr] = tanhf(acc[ns][r] + bia[ns]);
    __syncthreads();

    const size_t hbase = (size_t)(wave * 4 + b) * 262144;   // per (br,b) 256 KB
    #pragma unroll
    for (int it = 0; it < 2; ++it) {
        const int task = it * 64 + lane;
        const int sl = task >> 3;        // 0..15
        const int o  = task & 7;         // f-octet
        const int s  = s0 + sl;
        float v[8];
        *(float4*)&v[0] = *(const float4*)&ep[wave][sl][o * 8];
        *(float4*)&v[4] = *(const float4*)&ep[wave][sl][o * 8 + 4];
        unsigned short u[8];
        #pragma unroll
        for (int i = 0; i < 8; ++i) u[i] = (unsigned short)bfb(v[i]);
        uint4 pk;
        pk.x = (unsigned)u[0] | ((unsigned)u[1] << 16);
        pk.y = (unsigned)u[2] | ((unsigned)u[3] << 16);
        pk.z = (unsigned)u[4] | ((unsigned)u[5] << 16);
        pk.w = (unsigned)u[6] | ((unsigned)u[7] << 16);
        char* hka = hkB + hbase + (size_t)s * 128 +
                    (((unsigned)(o * 16)) ^ (((unsigned)(s & 7)) << 4));
        *(uint4*)hka = pk;
        char* hva = hvB + hbase + (size_t)(s >> 5) * 4096 + (o >> 1) * 1024 +
                    ((s >> 4) & 1) * 512 + ((s >> 2) & 3) * 128 +
                    (s & 3) * 32 + (o & 1) * 16;
        *(uint4*)hva = pk;
    }
}

// ---------------------------------------------------------------------------
// Kernel 2: bf16 MFMA flash attention, KVBLK=64, S-split x2, XCD-pinned grid,
// PV counted-lgkmcnt pipeline, fused Wf epilogue. NOW 4 blocks/CU.
// ---------------------------------------------------------------------------
#define TRREAD(dst, off) \
    asm volatile("ds_read_b64_tr_b16 %0, %1 offset:" #off \
                 : "=v"(dst) : "v"(vaddr));

typedef const __attribute__((address_space(1))) unsigned int* as1_u32p;
typedef __attribute__((address_space(3))) unsigned int* as3_u32p;

__device__ inline void gl_lds16(const void* g, unsigned lds_off) {
    __builtin_amdgcn_global_load_lds((as1_u32p)(uintptr_t)g,
                                     (as3_u32p)(uintptr_t)lds_off, 16, 0, 0);
}

__global__ __launch_bounds__(256, 4) void attn_mfma_kernel(
    const float* __restrict__ U3, const float* __restrict__ U5,
    const float* __restrict__ U7, const float* __restrict__ U9,
    const char* __restrict__ hkG, const char* __restrict__ hvG,
    const float* __restrict__ Wf,
    float* __restrict__ num, float* __restrict__ den)
{
    __shared__ unsigned short Kbuf[2][4096];   // 2 x 8KB (64s x 64f, XOR-swz)
    __shared__ unsigned short Vbuf[2][4096];   // 2 x 8KB (tr-subtiled)

    const int tid  = threadIdx.x;
    const int wave = tid >> 6;
    const int lane = tid & 63;
    const int g    = lane >> 4;
    const int lr   = lane & 15;

    // XCD-pinned decode: all 70 (ct,sc) blocks of one (br,b) on one XCD
    const int bid  = blockIdx.x;               // 0..1119
    const int xcd  = bid & 7;
    const int t2   = bid >> 3;                 // 0..139
    const int grp  = xcd + 8 * (t2 / 70);      // 0..15
    const int rest = t2 % 70;
    const int ct   = rest % 35;                // c-tile
    const int sc   = rest / 35;                // S-chunk half
    const int br   = grp >> 2;
    const int b    = grp & 3;
    const int c0   = ct * 256 + wave * 64;
    const int cb0  = sc * 16;                  // first 64-s chunk index

    const float* __restrict__ U =
        (br == 0) ? U3 : (br == 1) ? U5 : (br == 2) ? U7 : U9;

    // ---- Q fragments, phi(g,j) = g*8+j, pre-scaled by log2(e)
    bf16x8 Qf[4][2];
    #pragma unroll
    for (int cs = 0; cs < 4; ++cs) {
        int c = c0 + cs * 16 + lr;
        if (c > C_ - 1) c = C_ - 1;
        const float* Uc = U + (size_t)c * F_;
        #pragma unroll
        for (int kh = 0; kh < 2; ++kh) {
            const float4 lo = *(const float4*)(Uc + kh * 32 + g * 8);
            const float4 hi = *(const float4*)(Uc + kh * 32 + g * 8 + 4);
            bf16x8 q;
            q[0] = bfb(lo.x * LOG2E); q[1] = bfb(lo.y * LOG2E);
            q[2] = bfb(lo.z * LOG2E); q[3] = bfb(lo.w * LOG2E);
            q[4] = bfb(hi.x * LOG2E); q[5] = bfb(hi.y * LOG2E);
            q[6] = bfb(hi.z * LOG2E); q[7] = bfb(hi.w * LOG2E);
            Qf[cs][kh] = q;
        }
    }

    f32x4 acc[4][4];
    #pragma unroll
    for (int cs = 0; cs < 4; ++cs)
        #pragma unroll
        for (int fs = 0; fs < 4; ++fs)
            acc[cs][fs] = (f32x4){0.f, 0.f, 0.f, 0.f};
    float lsum[4] = {0.f, 0.f, 0.f, 0.f};

    const char* hkB = hkG + (size_t)grp * 262144;
    const char* hvB = hvG + (size_t)grp * 262144;
    const unsigned kL0 = (unsigned)(uintptr_t)&Kbuf[0][0];
    const unsigned vL0 = (unsigned)(uintptr_t)&Vbuf[0][0];

#define STAGEKV(chunk, buf) {                                              \
        const size_t go = (size_t)(chunk) * 8192 + wave * 2048 +           \
                          (size_t)(lane << 4);                             \
        const unsigned lo = (unsigned)((buf) * 8192 + wave * 2048);        \
        gl_lds16(hkB + go,        kL0 + lo);                               \
        gl_lds16(hkB + go + 1024, kL0 + lo + 1024);                        \
        gl_lds16(hvB + go,        vL0 + lo);                               \
        gl_lds16(hvB + go + 1024, vL0 + lo + 1024); }

    STAGEKV(cb0, 0)
    __syncthreads();

    const unsigned ksw = ((unsigned)(lr & 7)) << 4;

    for (int t = 0; t < 16; ++t) {
        const int cur = t & 1;
        if (t < 15) STAGEKV(cb0 + t + 1, cur ^ 1)

        // ---- K fragments: one ds_read_b128 each (phi(g,j)=g*8+j)
        const char* Kb = (const char*)Kbuf + cur * 8192;
        bf16x8 Kf[4][2];
        #pragma unroll
        for (int sh = 0; sh < 4; ++sh) {
            const unsigned rowb = (unsigned)((16 * sh + lr) * 128);
            #pragma unroll
            for (int kh = 0; kh < 2; ++kh)
                Kf[sh][kh] = *(const bf16x8*)(
                    Kb + rowb + (((unsigned)(kh * 64 + g * 16)) ^ ksw));
        }

        // ---- QK^T -> exp2 -> P fragments
        bf16x8 Pf[4][2];
        #pragma unroll
        for (int cs = 0; cs < 4; ++cs) {
            f32x4 d0 = (f32x4){0.f,0.f,0.f,0.f}, d1 = d0, d2 = d0, d3 = d0;
            __builtin_amdgcn_s_setprio(1);
            d0 = MFMA16(Kf[0][0], Qf[cs][0], d0);
            d0 = MFMA16(Kf[0][1], Qf[cs][1], d0);
            d1 = MFMA16(Kf[1][0], Qf[cs][0], d1);
            d1 = MFMA16(Kf[1][1], Qf[cs][1], d1);
            d2 = MFMA16(Kf[2][0], Qf[cs][0], d2);
            d2 = MFMA16(Kf[2][1], Qf[cs][1], d2);
            d3 = MFMA16(Kf[3][0], Qf[cs][0], d3);
            d3 = MFMA16(Kf[3][1], Qf[cs][1], d3);
            __builtin_amdgcn_s_setprio(0);
            float p[16];
            #pragma unroll
            for (int r = 0; r < 4; ++r) {
                p[r]      = EXP2F(d0[r]);
                p[4 + r]  = EXP2F(d1[r]);
                p[8 + r]  = EXP2F(d2[r]);
                p[12 + r] = EXP2F(d3[r]);
            }
            float sm = 0.f;
            #pragma unroll
            for (int r = 0; r < 16; ++r) sm += p[r];
            lsum[cs] += sm;
            bf16x8 pf0, pf1;
            #pragma unroll
            for (int r = 0; r < 8; ++r) { pf0[r] = bfb(p[r]); pf1[r] = bfb(p[8 + r]); }
            Pf[cs][0] = pf0;
            Pf[cs][1] = pf1;
        }

        // ---- PV: software-pipelined tr-reads (counted lgkmcnt), 2 reg groups
        const unsigned vaddr = vL0 + (unsigned)(cur * 8192 + g * 128 + lr * 2);
        {
            s16x4 pa, pb, pc, pd, qa, qb, qc, qd;
            __builtin_amdgcn_sched_barrier(0);   // pin: only TRREADs below
            TRREAD(pa, 0)    TRREAD(pb, 512)  TRREAD(pc, 4096) TRREAD(pd, 4608)
            TRREAD(qa, 1024) TRREAD(qb, 1536) TRREAD(qc, 5120) TRREAD(qd, 5632)
            asm volatile("s_waitcnt lgkmcnt(4)" ::: "memory");
            __builtin_amdgcn_sched_barrier(0);
            {
                const bf16x8 V0 = __builtin_shufflevector(pa, pb, 0,1,2,3,4,5,6,7);
                const bf16x8 V1 = __builtin_shufflevector(pc, pd, 0,1,2,3,4,5,6,7);
                __builtin_amdgcn_s_setprio(1);
                #pragma unroll
                for (int cs = 0; cs < 4; ++cs) {
                    acc[cs][0] = MFMA16(Pf[cs][0], V0, acc[cs][0]);
                    acc[cs][0] = MFMA16(Pf[cs][1], V1, acc[cs][0]);
                }
                __builtin_amdgcn_s_setprio(0);
            }
            TRREAD(pa, 2048) TRREAD(pb, 2560) TRREAD(pc, 6144) TRREAD(pd, 6656)
            asm volatile("s_waitcnt lgkmcnt(4)" ::: "memory");
            __builtin_amdgcn_sched_barrier(0);
            {
                const bf16x8 V0 = __builtin_shufflevector(qa, qb, 0,1,2,3,4,5,6,7);
                const bf16x8 V1 = __builtin_shufflevector(qc, qd, 0,1,2,3,4,5,6,7);
                __builtin_amdgcn_s_setprio(1);
                #pragma unroll
                for (int cs = 0; cs < 4; ++cs) {
                    acc[cs][1] = MFMA16(Pf[cs][0], V0, acc[cs][1]);
                    acc[cs][1] = MFMA16(Pf[cs][1], V1, acc[cs][1]);
                }
                __builtin_amdgcn_s_setprio(0);
            }
            TRREAD(qa, 3072) TRREAD(qb, 3584) TRREAD(qc, 7168) TRREAD(qd, 7680)
            asm volatile("s_waitcnt lgkmcnt(4)" ::: "memory");
            __builtin_amdgcn_sched_barrier(0);
            {
                const bf16x8 V0 = __builtin_shufflevector(pa, pb, 0,1,2,3,4,5,6,7);
                const bf16x8 V1 = __builtin_shufflevector(pc, pd, 0,1,2,3,4,5,6,7);
                __builtin_amdgcn_s_setprio(1);
                #pragma unroll
                for (int cs = 0; cs < 4; ++cs) {
                    acc[cs][2] = MFMA16(Pf[cs][0], V0, acc[cs][2]);
                    acc[cs][2] = MFMA16(Pf[cs][1], V1, acc[cs][2]);
                }
                __builtin_amdgcn_s_setprio(0);
            }
            asm volatile("s_waitcnt lgkmcnt(0)" ::: "memory");
            __builtin_amdgcn_sched_barrier(0);
            {
                const bf16x8 V0 = __builtin_shufflevector(qa, qb, 0,1,2,3,4,5,6,7);
                const bf16x8 V1 = __builtin_shufflevector(qc, qd, 0,1,2,3,4,5,6,7);
                __builtin_amdgcn_s_setprio(1);
                #pragma unroll
                for (int cs = 0; cs < 4; ++cs) {
                    acc[cs][3] = MFMA16(Pf[cs][0], V0, acc[cs][3]);
                    acc[cs][3] = MFMA16(Pf[cs][1], V1, acc[cs][3]);
                }
                __builtin_amdgcn_s_setprio(0);
            }
        }

        __syncthreads();
    }

    // ---- denominators: reduce over g-groups, atomicAdd into den
    #pragma unroll
    for (int cs = 0; cs < 4; ++cs) {
        lsum[cs] += __shfl_xor(lsum[cs], 16);
        lsum[cs] += __shfl_xor(lsum[cs], 32);
        if (g == 0) {
            const int cden = c0 + cs * 16 + lr;
            if (cden < C_)
                atomicAdd(&den[(size_t)grp * C_ + cden], lsum[cs]);
        }
    }

    // ---- numerators: unnormalized Wf-dot, 16-lane reduce, atomicAdd
    #pragma unroll
    for (int cs = 0; cs < 4; ++cs) {
        #pragma unroll
        for (int r = 0; r < 4; ++r) {
            const int cc = c0 + cs * 16 + 4 * g + r;
            const int c  = (cc < C_) ? cc : (C_ - 1);
            const float* wrow = Wf + (size_t)c * (4 * F_) + br * F_ + lr;
            float p = 0.f;
            #pragma unroll
            for (int fs = 0; fs < 4; ++fs)
                p += acc[cs][fs][r] * wrow[fs * 16];
            p += __shfl_xor(p, 1);
            p += __shfl_xor(p, 2);
            p += __shfl_xor(p, 4);
            p += __shfl_xor(p, 8);
            if (lr == 0 && cc < C_)
                atomicAdd(&num[(size_t)grp * C_ + cc], p);
        }
    }
}

// ---------------------------------------------------------------------------
// Kernel 3: yh = sum_br num/den + bf; BCE; fused final loss via last-block
// ---------------------------------------------------------------------------
__global__ __launch_bounds__(256) void bce_kernel(
    const float* __restrict__ num, const float* __restrict__ den,
    const float* __restrict__ bf, const float* __restrict__ y,
    float* __restrict__ out, float* __restrict__ lossAcc,
    int* __restrict__ counter)
{
    const int p = blockIdx.x * 256 + threadIdx.x;
    float bce = 0.f;
    if (p < B_ * C_) {
        const int b = p / C_;
        const int c = p - b * C_;
        float yh = bf[c];
        #pragma unroll
        for (int br = 0; br < 4; ++br) {
            const size_t i = (size_t)(br * 4 + b) * C_ + c;
            yh += num[i] / den[i];
        }
        out[p] = yh;
        bce = fmaxf(yh, 0.f) - yh * y[p] + log1pf(expf(-fabsf(yh)));
    }
    __shared__ float red[256];
    red[threadIdx.x] = bce;
    __syncthreads();
    #pragma unroll
    for (int stp = 128; stp > 0; stp >>= 1) {
        if (threadIdx.x < stp) red[threadIdx.x] += red[threadIdx.x + stp];
        __syncthreads();
    }
    if (threadIdx.x == 0) {
        atomicAdd(lossAcc, red[0]);
        __threadfence();
        const int done = atomicAdd(counter, 1);
        if (done == (int)gridDim.x - 1) {
            __threadfence();
            const float total = atomicAdd(lossAcc, 0.f);   // read via L2
            out[B_ * C_] = total / (float)(B_ * C_);
        }
    }
}

// ---------------------------------------------------------------------------
extern "C" void kernel_launch(void* const* d_in, const int* in_sizes, int n_in,
                              void* d_out, int out_size, void* d_ws, size_t ws_size,
                              hipStream_t stream)
{
    const int*   x     = (const int*)  d_in[0];
    const float* y     = (const float*)d_in[1];
    const float* embed = (const float*)d_in[2];
    const float* w3    = (const float*)d_in[3];
    const float* b3    = (const float*)d_in[4];
    const float* w5    = (const float*)d_in[5];
    const float* b5    = (const float*)d_in[6];
    const float* w7    = (const float*)d_in[7];
    const float* b7    = (const float*)d_in[8];
    const float* w9    = (const float*)d_in[9];
    const float* b9    = (const float*)d_in[10];
    const float* U3    = (const float*)d_in[11];
    const float* U5    = (const float*)d_in[12];
    const float* U7    = (const float*)d_in[13];
    const float* U9    = (const float*)d_in[14];
    const float* Wf    = (const float*)d_in[15];
    const float* bfv   = (const float*)d_in[16];

    char* wsb = (char*)d_ws;
    float*          num      = (float*)wsb;                     // 142752 f
    float*          den      = (float*)(wsb + 571008);          // 142752 f
    float*          lossAcc  = (float*)(wsb + 1142016);
    int*            counter  = (int*)  (wsb + 1142020);
    unsigned short* Wp       = (unsigned short*)(wsb + 1142592);// 294912 bf16
    char*           hkB      = wsb + 1732608;                   // 4 MB
    char*           hvB      = wsb + 1732608 + 4194304;         // 4 MB
    float*          out      = (float*)d_out;

    prep_kernel<<<1152, 256, 0, stream>>>(w3, w5, w7, w9, Wp, num, den,
                                          lossAcc, counter);

    conv_mfma_kernel<<<512, 256, 0, stream>>>(
        x, embed, Wp, b3, b5, b7, b9, hkB, hvB);

    attn_mfma_kernel<<<1120, 256, 0, stream>>>(U3, U5, U7, U9, hkB, hvB, Wf,
                                               num, den);

    const int nblk = (B_ * C_ + 255) / 256;   // 140
    bce_kernel<<<nblk, 256, 0, stream>>>(num, den, bfv, y, out,
                                         lossAcc, counter);
}